// Round 2
// baseline (3641.655 us; speedup 1.0000x reference)
//
#include <hip/hip_runtime.h>
#include <hip/hip_bf16.h>
#include <math.h>

#define NN 50000
#define NE 400000

// ---------- GEMM: out[r,c] (beta?+=:=) rowscale[r]*(X[r,0:128]@W[0:128,c]) + bias[c] ----------
// W row-major [128][ldw-slice of 128 cols]; grid ceil(n/32), block 256.
__global__ __launch_bounds__(256) void gemm128_kernel(
    const float* __restrict__ X, int lda,
    const float* __restrict__ W, int ldw,
    const float* __restrict__ bias,
    const float* __restrict__ rowscale,
    float* __restrict__ out, int ldo,
    int n_rows, int beta)
{
  __shared__ float xs[32][128];
  const int t = threadIdx.x;
  const int row0 = blockIdx.x * 32;
  for (int idx = t; idx < 4096; idx += 256) {
    int rr = idx >> 7, kk = idx & 127;
    int r = row0 + rr;
    xs[rr][kk] = (r < n_rows) ? X[(size_t)r * lda + kk] : 0.0f;
  }
  __syncthreads();
  const int cw = t & 31;   // 32 col groups of 4
  const int rg = t >> 5;   // 8 row groups of 4
  float acc[4][4];
#pragma unroll
  for (int rr = 0; rr < 4; ++rr)
#pragma unroll
    for (int cc = 0; cc < 4; ++cc) acc[rr][cc] = 0.0f;

  for (int k = 0; k < 128; ++k) {
    float4 w4 = *(const float4*)(W + (size_t)k * ldw + cw * 4);
    const float wv[4] = {w4.x, w4.y, w4.z, w4.w};
    float xr[4];
#pragma unroll
    for (int rr = 0; rr < 4; ++rr) xr[rr] = xs[rg * 4 + rr][k];
#pragma unroll
    for (int rr = 0; rr < 4; ++rr)
#pragma unroll
      for (int cc = 0; cc < 4; ++cc) acc[rr][cc] = fmaf(xr[rr], wv[cc], acc[rr][cc]);
  }
  float bvv[4] = {0.f, 0.f, 0.f, 0.f};
  if (bias) {
    float4 b4 = *(const float4*)(bias + cw * 4);
    bvv[0] = b4.x; bvv[1] = b4.y; bvv[2] = b4.z; bvv[3] = b4.w;
  }
#pragma unroll
  for (int rr = 0; rr < 4; ++rr) {
    int r = row0 + rg * 4 + rr;
    if (r < n_rows) {
      float scale = rowscale ? rowscale[r] : 1.0f;
      float* op = out + (size_t)r * ldo + cw * 4;
      float4 val;
      val.x = acc[rr][0] * scale + bvv[0];
      val.y = acc[rr][1] * scale + bvv[1];
      val.z = acc[rr][2] * scale + bvv[2];
      val.w = acc[rr][3] * scale + bvv[3];
      if (beta) {
        float4 old = *(const float4*)op;
        val.x += old.x; val.y += old.y; val.z += old.z; val.w += old.w;
      }
      *(float4*)op = val;
    }
  }
}

// ---------- CSR build ----------
__global__ void zero_int_kernel(int* __restrict__ p, int n) {
  int i = blockIdx.x * 256 + threadIdx.x;
  if (i < n) p[i] = 0;
}
__global__ void hist_kernel(const int* __restrict__ dst, int* __restrict__ deg) {
  int e = blockIdx.x * 256 + threadIdx.x;
  if (e < NE) atomicAdd(&deg[dst[e]], 1);
}
__global__ void scan_kernel(const int* __restrict__ deg, int* __restrict__ rowstart) {
  __shared__ int sd[256];
  __shared__ int carry;
  const int t = threadIdx.x;
  if (t == 0) { carry = 0; rowstart[0] = 0; }
  __syncthreads();
  for (int base = 0; base < NN; base += 256) {
    sd[t] = (base + t < NN) ? deg[base + t] : 0;
    __syncthreads();
    for (int o = 1; o < 256; o <<= 1) {
      int val = (t >= o) ? sd[t - o] : 0;
      __syncthreads();
      sd[t] += val;
      __syncthreads();
    }
    if (base + t < NN) rowstart[base + t + 1] = carry + sd[t];
    __syncthreads();
    if (t == 0) carry += sd[255];
    __syncthreads();
  }
}
__global__ void copy_int_kernel(const int* __restrict__ a, int* __restrict__ b, int n) {
  int i = blockIdx.x * 256 + threadIdx.x;
  if (i < n) b[i] = a[i];
}
__global__ void scatter_kernel(const int* __restrict__ dst, int* __restrict__ cursor,
                               int* __restrict__ elist) {
  int e = blockIdx.x * 256 + threadIdx.x;
  if (e < NE) {
    int pos = atomicAdd(&cursor[dst[e]], 1);
    elist[pos] = e;
  }
}
__global__ void permute_kernel(const int* __restrict__ elist, const int* __restrict__ src,
                               const float* __restrict__ dirw, const float* __restrict__ geo,
                               int* __restrict__ srcp, float* __restrict__ dirp,
                               float* __restrict__ geop) {
  int ii = blockIdx.x * 256 + threadIdx.x;
  if (ii >= NE) return;
  int e = elist[ii];
  srcp[ii] = src[e];
  dirp[ii] = dirw[e];
  if (geop) {
    for (int j = 0; j < 20; ++j) geop[(size_t)ii * 20 + j] = geo[(size_t)e * 20 + j];
  }
}
__global__ void swc_kernel(const int* __restrict__ deg, float* __restrict__ swc) {
  int n = blockIdx.x * 256 + threadIdx.x;
  if (n < NN) swc[n] = deg[n] ? 1.0f : 0.0f;
}

// ---------- per-layer weight prep (all tiny mats from Wee/bee/We_i/be_i) ----------
// mats layout (floats): M2T[3][128][128] @0; M34T[3][128][24] @49152; WW2[3][128][128] @58368;
//                       WWg[3][21][128] @107520; bvec[3][128] @115584; Wsum0[128][128] @115968; total 132352
__global__ void prep_kernel(const float* __restrict__ Wee, const float* __restrict__ bee,
                            const float* __restrict__ We, const float* __restrict__ be,
                            float* __restrict__ mats)
{
  int idx = blockIdx.x * 256 + threadIdx.x;
  if (idx >= 132352) return;
  float acc = 0.0f;
  if (idx < 49152) {                       // M2T[h][c][u] = sum_j We[j,hc]*Wee[128+u,j]
    int h = idx >> 14, rem = idx & 16383, c = rem >> 7, u = rem & 127;
    for (int j = 0; j < 128; ++j)
      acc += We[(size_t)j * 384 + h * 128 + c] * Wee[(size_t)(128 + u) * 128 + j];
    mats[idx] = acc;
  } else if (idx < 58368) {                // M34T[h][c][u24]
    int r = idx - 49152; int h = r / 3072; int rem = r - h * 3072; int c = rem / 24; int u = rem - c * 24;
    if (u < 21) {
      int trow = (u < 20) ? (257 + u) : 256;
      for (int j = 0; j < 128; ++j)
        acc += We[(size_t)j * 384 + h * 128 + c] * Wee[(size_t)trow * 128 + j];
    }
    mats[idx] = acc;
  } else if (idx < 107520) {               // WW2[h][t][c] = sum_j Wee[128+t,j]*We[j,hc]
    int r = idx - 58368; int h = r >> 14; int rem = r & 16383; int t = rem >> 7; int c = rem & 127;
    for (int j = 0; j < 128; ++j)
      acc += Wee[(size_t)(128 + t) * 128 + j] * We[(size_t)j * 384 + h * 128 + c];
    mats[idx] = acc;
  } else if (idx < 115584) {               // WWg[h][t21][c] rows: t<20 -> 257+t ; t=20 -> 256
    int r = idx - 107520; int h = r / 2688; int rem = r - h * 2688; int t = rem >> 7; int c = rem & 127;
    int trow = (t < 20) ? (257 + t) : 256;
    for (int j = 0; j < 128; ++j)
      acc += Wee[(size_t)trow * 128 + j] * We[(size_t)j * 384 + h * 128 + c];
    mats[idx] = acc;
  } else if (idx < 115968) {               // bvec[h][c] = bee@We_h + be_h
    int r = idx - 115584; int h = r >> 7; int c = r & 127;
    for (int j = 0; j < 128; ++j)
      acc += bee[j] * We[(size_t)j * 384 + h * 128 + c];
    mats[idx] = acc + be[h * 128 + c];
  } else {                                 // Wsum0[t][c] = (1/3) sum_h Wee[t,:]@We[:,hc]
    int r = idx - 115968; int t = r >> 7; int c = r & 127;
    for (int j = 0; j < 128; ++j)
      acc += Wee[(size_t)t * 128 + j] *
             (We[(size_t)j * 384 + c] + We[(size_t)j * 384 + 128 + c] + We[(size_t)j * 384 + 256 + c]);
    mats[idx] = acc * (1.0f / 3.0f);
  }
}

// ---------- g34 = qh @ M34T  [N,24] ----------
__global__ __launch_bounds__(256) void g34_kernel(const float* __restrict__ qh,
                                                  const float* __restrict__ M34T,
                                                  float* __restrict__ g34)
{
  __shared__ float xs[32][128];
  const int n0 = blockIdx.x * 32;
  const int t = threadIdx.x;
  for (int idx = t; idx < 4096; idx += 256) {
    int rr = idx >> 7, kk = idx & 127;
    int n = n0 + rr;
    xs[rr][kk] = (n < NN) ? qh[(size_t)n * 128 + kk] : 0.0f;
  }
  __syncthreads();
  const int rr = t >> 3;
  const int ub = (t & 7) * 3;
  float a0 = 0.f, a1 = 0.f, a2 = 0.f;
  for (int k = 0; k < 128; ++k) {
    float x = xs[rr][k];
    const float* w = M34T + (size_t)k * 24 + ub;
    a0 = fmaf(x, w[0], a0); a1 = fmaf(x, w[1], a1); a2 = fmaf(x, w[2], a2);
  }
  int n = n0 + rr;
  if (n < NN) {
    g34[(size_t)n * 24 + ub] = a0;
    g34[(size_t)n * 24 + ub + 1] = a1;
    g34[(size_t)n * 24 + ub + 2] = a2;
  }
}

// ---------- per-head attention: online softmax over CSR(dst), wave per node ----------
__global__ __launch_bounds__(256) void attn_kernel(
    const float* __restrict__ qh, const float* __restrict__ kh,
    const float* __restrict__ vh, const float* __restrict__ h0,
    float* __restrict__ g2h,                 // in: g2 ; out: fs2 (own-row alias)
    const float* __restrict__ g34h,
    const int* __restrict__ rowstart,
    const int* __restrict__ srcp, const float* __restrict__ dirp,
    const float* __restrict__ geop,          // may be null
    const int* __restrict__ elist, const float* __restrict__ geo,  // fallback path
    const float* __restrict__ WWg, const float* __restrict__ bvec,
    float* __restrict__ tmp1)
{
  const int lane = threadIdx.x & 63;
  const int n = blockIdx.x * 4 + (threadIdx.x >> 6);
  if (n >= NN) return;
  const size_t nb = (size_t)n * 128;
  const float q0 = qh[nb + lane], q1 = qh[nb + 64 + lane];
  const float ga0 = g2h[nb + lane], ga1 = g2h[nb + 64 + lane];
  const float g34v = (lane < 21) ? g34h[(size_t)n * 24 + lane] : 0.0f;
  const int beg = rowstart[n], end = rowstart[n + 1];
  const float rsC = 0.088388347648318447f;   // 1/sqrt(128)
  float m = -INFINITY, den = 0.f;
  float F2a = 0.f, F2b = 0.f, f34 = 0.f, fva = 0.f, fvb = 0.f;
  for (int ii = beg; ii < end; ++ii) {
    const int s = srcp[ii];
    const float d = dirp[ii];
    const size_t sb = (size_t)s * 128;
    const float k0 = kh[sb + lane], k1 = kh[sb + 64 + lane];
    const float ha = h0[sb + lane], hb = h0[sb + 64 + lane];
    float geoval = 0.0f;
    if (geop) {
      if (lane < 20) geoval = geop[(size_t)ii * 20 + lane];
    } else {
      int e = elist[ii];
      if (lane < 20) geoval = geo[(size_t)e * 20 + lane];
    }
    float t = q0 * k0 + q1 * k1 + d * (ga0 * ha + ga1 * hb);
    if (lane < 20) t += geoval * g34v;
    else if (lane == 20) t += d * g34v;
#pragma unroll
    for (int off = 1; off < 64; off <<= 1) t += __shfl_xor(t, off);
    const float alpha = t * rsC;
    if (alpha > m) {
      const float f = __expf(m - alpha);   // m=-inf first time -> f=0
      den *= f; F2a *= f; F2b *= f; f34 *= f; fva *= f; fvb *= f;
      m = alpha;
    }
    const float w = __expf(alpha - m);
    const float v0 = vh[sb + lane], v1 = vh[sb + 64 + lane];
    const float wd = w * d;
    den += w;
    F2a = fmaf(wd, ha, F2a); F2b = fmaf(wd, hb, F2b);
    if (lane < 20) f34 = fmaf(w, geoval, f34);
    else if (lane == 20) f34 += wd;
    fva = fmaf(w, v0, fva); fvb = fmaf(w, v1, fvb);
  }
  const float sc = (1.0f / 3.0f) / (den + 1e-16f);   // head-mean folded
  g2h[nb + lane] = F2a * sc;
  g2h[nb + 64 + lane] = F2b * sc;
  f34 *= sc;
  fva *= sc; fvb *= sc;
#pragma unroll
  for (int t2 = 0; t2 < 21; ++t2) {
    const float ft = __shfl(f34, t2);
    fva = fmaf(ft, WWg[t2 * 128 + lane], fva);
    fvb = fmaf(ft, WWg[t2 * 128 + 64 + lane], fvb);
  }
  const float swh = den * sc;                // = 1/3 (connected) or 0 (isolated)
  fva = fmaf(swh, bvec[lane], fva);
  fvb = fmaf(swh, bvec[64 + lane], fvb);
  tmp1[nb + lane] += fva;
  tmp1[nb + 64 + lane] += fvb;
}

// ---------- finalize: xn = relu(tmp1 + resid) ----------
__global__ void finalize_kernel(const float* __restrict__ tmp1,
                                const float* __restrict__ resid,
                                float* __restrict__ xn)
{
  int i = blockIdx.x * 256 + threadIdx.x;
  if (i >= NN * 32) return;
  float4 a = ((const float4*)tmp1)[i];
  float4 b = ((const float4*)resid)[i];
  float4 r;
  r.x = fmaxf(a.x + b.x, 0.f); r.y = fmaxf(a.y + b.y, 0.f);
  r.z = fmaxf(a.z + b.z, 0.f); r.w = fmaxf(a.w + b.w, 0.f);
  ((float4*)xn)[i] = r;
}

extern "C" void kernel_launch(void* const* d_in, const int* in_sizes, int n_in,
                              void* d_out, int out_size, void* d_ws, size_t ws_size,
                              hipStream_t stream)
{
  (void)in_sizes; (void)n_in; (void)out_size;
  const float* h    = (const float*)d_in[0];
  const float* geo  = (const float*)d_in[1];
  const float* dirw = (const float*)d_in[2];
  const int*   src  = (const int*)d_in[3];
  const int*   dst  = (const int*)d_in[4];
  const float* Wee  = (const float*)d_in[5];
  const float* bee  = (const float*)d_in[6];
  const float* Wres = (const float*)d_in[7];
  const float* bres = (const float*)d_in[8];
  const float* Wq   = (const float*)d_in[9];
  const float* bq   = (const float*)d_in[10];
  const float* Wk   = (const float*)d_in[11];
  const float* bk   = (const float*)d_in[12];
  const float* Wv   = (const float*)d_in[13];
  const float* bv   = (const float*)d_in[14];
  const float* We   = (const float*)d_in[15];
  const float* be   = (const float*)d_in[16];
  const float* Ws   = (const float*)d_in[17];
  const float* bs   = (const float*)d_in[18];
  const float* Wctr = (const float*)d_in[19];
  const float* bctr = (const float*)d_in[20];
  float* tmp1 = (float*)d_out;           // d_out doubles as the per-layer accumulator

  // ---- workspace layout (floats first, then ints, then optional geop) ----
  float* F = (float*)d_ws;
  size_t off = 0;
  float* qh   = F + off; off += 6400000;
  float* kh   = F + off; off += 6400000;
  float* vh   = F + off; off += 6400000;
  float* g2h  = F + off; off += 6400000;
  float* g34h = F + off; off += 1200000;
  float* swc  = F + off; off += 50048;
  float* bufA = F + off; off += 6400000;
  float* bufB = F + off; off += 6400000;
  float* mats = F + off; off += 132352;
  float* dirp = F + off; off += 400000;
  int* deg      = (int*)(F + off);
  int* rowstart = deg + 50000;
  int* cursor   = rowstart + 50004;
  int* elist    = cursor + 50000;
  int* srcp     = elist + 400000;
  size_t base_bytes = ((char*)(srcp + 400000)) - ((char*)d_ws);
  float* geop = nullptr;
  if (ws_size >= base_bytes + (size_t)NE * 20 * sizeof(float))
    geop = (float*)((char*)d_ws + base_bytes);

  // ---- CSR by dst + permuted edge arrays ----
  zero_int_kernel<<<(NN + 255) / 256, 256, 0, stream>>>(deg, NN);
  hist_kernel<<<(NE + 255) / 256, 256, 0, stream>>>(dst, deg);
  scan_kernel<<<1, 256, 0, stream>>>(deg, rowstart);
  copy_int_kernel<<<(NN + 255) / 256, 256, 0, stream>>>(rowstart, cursor, NN);
  scatter_kernel<<<(NE + 255) / 256, 256, 0, stream>>>(dst, cursor, elist);
  permute_kernel<<<(NE + 255) / 256, 256, 0, stream>>>(elist, src, dirw, geo, srcp, dirp, geop);
  swc_kernel<<<(NN + 255) / 256, 256, 0, stream>>>(deg, swc);

  const int gN = (NN + 31) / 32;
  // layer-0 residual -> bufB
  gemm128_kernel<<<gN, 256, 0, stream>>>(h, 128, Wres, 128, bres, nullptr, bufB, 128, NN, 0);

  const float* x = h;
  float* xn = bufA;
  for (int i = 0; i < 3; ++i) {
    const float* We_i = We + (size_t)i * 49152;
    prep_kernel<<<(132352 + 255) / 256, 256, 0, stream>>>(Wee, bee, We_i, be + i * 384, mats);
    // tmp1 = x@Ws + bs
    gemm128_kernel<<<gN, 256, 0, stream>>>(x, 128, Ws + (size_t)i * 16384, 128, bs + i * 128,
                                           nullptr, tmp1, 128, NN, 0);
    // tmp1 += mask * (h0 @ Wsum0)   (the sum_h (1/3)*h[dst]-feature message term)
    gemm128_kernel<<<gN, 256, 0, stream>>>(h, 128, mats + 115968, 128, nullptr, swc,
                                           tmp1, 128, NN, 1);
    for (int hh = 0; hh < 3; ++hh) {
      const float* M2T  = mats + (size_t)hh * 16384;
      const float* M34T = mats + 49152 + (size_t)hh * 3072;
      const float* WW2  = mats + 58368 + (size_t)hh * 16384;
      const float* WWg  = mats + 107520 + (size_t)hh * 2688;
      const float* bvec = mats + 115584 + (size_t)hh * 128;
      gemm128_kernel<<<gN, 256, 0, stream>>>(x, 128, Wq + (size_t)i * 49152 + hh * 128, 384,
                                             bq + i * 384 + hh * 128, nullptr, qh, 128, NN, 0);
      gemm128_kernel<<<gN, 256, 0, stream>>>(x, 128, Wk + (size_t)i * 49152 + hh * 128, 384,
                                             bk + i * 384 + hh * 128, nullptr, kh, 128, NN, 0);
      gemm128_kernel<<<gN, 256, 0, stream>>>(x, 128, Wv + (size_t)i * 49152 + hh * 128, 384,
                                             bv + i * 384 + hh * 128, nullptr, vh, 128, NN, 0);
      gemm128_kernel<<<gN, 256, 0, stream>>>(qh, 128, M2T, 128, nullptr, nullptr, g2h, 128, NN, 0);
      g34_kernel<<<gN, 256, 0, stream>>>(qh, M34T, g34h);
      attn_kernel<<<(NN + 3) / 4, 256, 0, stream>>>(qh, kh, vh, h, g2h, g34h, rowstart,
                                                    srcp, dirp, geop, elist, geo, WWg, bvec, tmp1);
      // tmp1 += fs2 @ WW2
      gemm128_kernel<<<gN, 256, 0, stream>>>(g2h, 128, WW2, 128, nullptr, nullptr, tmp1, 128, NN, 1);
    }
    const float* rptr = (i == 0) ? bufB : x;
    finalize_kernel<<<(NN * 32 + 255) / 256, 256, 0, stream>>>(tmp1, rptr, xn);
    x = xn;
    xn = (i == 0) ? bufB : bufA;
  }
  // out = concat(h, h_final) @ Wctr + bctr   (tmp1 == d_out is dead now; overwrite)
  gemm128_kernel<<<gN, 256, 0, stream>>>(h, 128, Wctr, 128, bctr, nullptr, tmp1, 128, NN, 0);
  gemm128_kernel<<<gN, 256, 0, stream>>>(x, 128, Wctr + 16384, 128, nullptr, nullptr, tmp1, 128, NN, 1);
}

// Round 3
// 1762.143 us; speedup vs baseline: 2.0666x; 2.0666x over previous
//
#include <hip/hip_runtime.h>
#include <math.h>

#define NN 50000
#define NE 400000

typedef _Float16 f16;
typedef _Float16 f16x8 __attribute__((ext_vector_type(8)));
typedef _Float16 f16x4 __attribute__((ext_vector_type(4)));
typedef float f32x4 __attribute__((ext_vector_type(4)));

// ================= MFMA fp16 GEMM =================
// A [M][lda] f16, WT [Ntot][K] f16 (row-major, = W^T), out f32 and/or f16.
// Block: 256 thr = 4 waves; tile M=128 (wave=32 rows), N=64 cols; K chunks of 128.
// cols < split_col -> outb (f16, ldb, + z*zB); cols >= split -> outf (f32, ldf, col-split).
__global__ __launch_bounds__(256) void hgemm_kernel(
    const f16* __restrict__ A, int lda,
    const f16* __restrict__ WT, int K,
    const float* __restrict__ bias,
    const float* __restrict__ rowscale,
    float* __restrict__ outf, int ldf,
    f16* __restrict__ outb, int ldb,
    int split_col, int M, int beta,
    int zA, int zW, int zB)
{
  __shared__ f16 As[128 * 128];
  __shared__ f16 Bs[64 * 128];
  const int t = threadIdx.x;
  const int wv = t >> 6, lane = t & 63;
  const int l15 = lane & 15, l4 = lane >> 4;
  const int row0 = blockIdx.x * 128;
  const int col0 = blockIdx.y * 64;
  const int z = blockIdx.z;
  A  += (size_t)z * zA;
  WT += (size_t)z * zW;

  f32x4 acc[2][4];
#pragma unroll
  for (int m = 0; m < 2; ++m)
#pragma unroll
    for (int n = 0; n < 4; ++n) acc[m][n] = (f32x4){0.f, 0.f, 0.f, 0.f};

  for (int kc = 0; kc < K; kc += 128) {
    for (int i = t; i < 2048; i += 256) {           // stage A 128x128 f16
      int r = i >> 4, c8 = i & 15;
      int gr = row0 + r;
      float4 v = make_float4(0.f, 0.f, 0.f, 0.f);
      if (gr < M) v = *(const float4*)(A + (size_t)gr * lda + kc + c8 * 8);
      *(float4*)(As + r * 128 + ((c8 ^ (r & 15)) << 3)) = v;
    }
    for (int i = t; i < 1024; i += 256) {           // stage B 64x128 f16
      int c = i >> 4, c8 = i & 15;
      float4 v = *(const float4*)(WT + (size_t)(col0 + c) * K + kc + c8 * 8);
      *(float4*)(Bs + c * 128 + ((c8 ^ (c & 15)) << 3)) = v;
    }
    __syncthreads();
#pragma unroll
    for (int ks = 0; ks < 4; ++ks) {
      const int co = (((ks * 4 + l4) ^ l15) << 3);  // row&15 == l15 for all frags
      f16x8 a0 = *(const f16x8*)(As + (wv * 32 +      l15) * 128 + co);
      f16x8 a1 = *(const f16x8*)(As + (wv * 32 + 16 + l15) * 128 + co);
      f16x8 b0 = *(const f16x8*)(Bs + (     l15) * 128 + co);
      f16x8 b1 = *(const f16x8*)(Bs + (16 + l15) * 128 + co);
      f16x8 b2 = *(const f16x8*)(Bs + (32 + l15) * 128 + co);
      f16x8 b3 = *(const f16x8*)(Bs + (48 + l15) * 128 + co);
      acc[0][0] = __builtin_amdgcn_mfma_f32_16x16x32_f16(a0, b0, acc[0][0], 0, 0, 0);
      acc[0][1] = __builtin_amdgcn_mfma_f32_16x16x32_f16(a0, b1, acc[0][1], 0, 0, 0);
      acc[0][2] = __builtin_amdgcn_mfma_f32_16x16x32_f16(a0, b2, acc[0][2], 0, 0, 0);
      acc[0][3] = __builtin_amdgcn_mfma_f32_16x16x32_f16(a0, b3, acc[0][3], 0, 0, 0);
      acc[1][0] = __builtin_amdgcn_mfma_f32_16x16x32_f16(a1, b0, acc[1][0], 0, 0, 0);
      acc[1][1] = __builtin_amdgcn_mfma_f32_16x16x32_f16(a1, b1, acc[1][1], 0, 0, 0);
      acc[1][2] = __builtin_amdgcn_mfma_f32_16x16x32_f16(a1, b2, acc[1][2], 0, 0, 0);
      acc[1][3] = __builtin_amdgcn_mfma_f32_16x16x32_f16(a1, b3, acc[1][3], 0, 0, 0);
    }
    __syncthreads();
  }

  float bv4[4];
#pragma unroll
  for (int n = 0; n < 4; ++n) bv4[n] = bias ? bias[col0 + n * 16 + l15] : 0.f;
#pragma unroll
  for (int m = 0; m < 2; ++m) {
#pragma unroll
    for (int j = 0; j < 4; ++j) {
      int r = row0 + wv * 32 + m * 16 + l4 * 4 + j;
      if (r >= M) continue;
      float rsv = rowscale ? rowscale[r] : 1.f;
#pragma unroll
      for (int n = 0; n < 4; ++n) {
        int c = col0 + n * 16 + l15;
        float val = acc[m][n][j] * rsv + bv4[n];
        if (c < split_col) {
          outb[(size_t)r * ldb + (size_t)z * zB + c] = (f16)val;
        } else {
          float* p = outf + (size_t)r * ldf + (c - split_col);
          *p = (beta ? *p : 0.f) + val;
        }
      }
    }
  }
}

// ================= CSR build =================
__global__ void zero_int_kernel(int* __restrict__ p, int n) {
  int i = blockIdx.x * 256 + threadIdx.x;
  if (i < n) p[i] = 0;
}
__global__ void hist_kernel(const int* __restrict__ dst, int* __restrict__ deg) {
  int e = blockIdx.x * 256 + threadIdx.x;
  if (e < NE) atomicAdd(&deg[dst[e]], 1);
}
__global__ void scanA_kernel(const int* __restrict__ deg, int* __restrict__ rowstart,
                             int* __restrict__ part) {
  __shared__ int sd[256];
  int b = blockIdx.x, t = threadIdx.x, i = b * 256 + t;
  sd[t] = (i < NN) ? deg[i] : 0;
  __syncthreads();
  for (int o = 1; o < 256; o <<= 1) {
    int v = (t >= o) ? sd[t - o] : 0;
    __syncthreads();
    sd[t] += v;
    __syncthreads();
  }
  if (i < NN) rowstart[i + 1] = sd[t];
  if (t == 255) part[b] = sd[255];
}
__global__ void scanB_kernel(int* __restrict__ part, int nb) {
  __shared__ int sd[256];
  int t = threadIdx.x;
  sd[t] = (t < nb) ? part[t] : 0;
  __syncthreads();
  for (int o = 1; o < 256; o <<= 1) {
    int v = (t >= o) ? sd[t - o] : 0;
    __syncthreads();
    sd[t] += v;
    __syncthreads();
  }
  if (t < nb) part[t] = sd[t];
}
__global__ void scanC_kernel(const int* __restrict__ deg, int* __restrict__ rowstart,
                             const int* __restrict__ part, int* __restrict__ cursor) {
  int b = blockIdx.x, t = threadIdx.x, i = b * 256 + t;
  if (i >= NN) return;
  int off = b ? part[b - 1] : 0;
  int fin = rowstart[i + 1] + off;
  rowstart[i + 1] = fin;
  cursor[i] = fin - deg[i];
  if (i == 0) rowstart[0] = 0;
}
__global__ void scatter_kernel(const int* __restrict__ dst, int* __restrict__ cursor,
                               int* __restrict__ elist) {
  int e = blockIdx.x * 256 + threadIdx.x;
  if (e < NE) {
    int pos = atomicAdd(&cursor[dst[e]], 1);
    elist[pos] = e;
  }
}
__global__ void permute_kernel(const int* __restrict__ elist, const int* __restrict__ src,
                               const float* __restrict__ dirw,
                               int* __restrict__ srcp, f16* __restrict__ dirpb) {
  int ii = blockIdx.x * 256 + threadIdx.x;
  if (ii >= NE) return;
  int e = elist[ii];
  srcp[ii] = src[e];
  dirpb[ii] = (f16)dirw[e];
}
__global__ void swc_kernel(const int* __restrict__ deg, float* __restrict__ swc) {
  int n = blockIdx.x * 256 + threadIdx.x;
  if (n < NN) swc[n] = deg[n] ? 1.0f : 0.0f;
}

// ================= per-layer weight prep (fp32 math, proven in round 2) =================
// mats: M2T[3][128(k)][128(u)] @0; M34T[3][128(k)][24] @49152; WW2[3][128(t)][128(c)] @58368;
//       WWg[3][21][128] @107520; bvec[3][128] @115584; Wsum0[128(k)][128(c)] @115968
__global__ void prep_kernel(const float* __restrict__ Wee, const float* __restrict__ bee,
                            const float* __restrict__ We, const float* __restrict__ be,
                            float* __restrict__ mats)
{
  int idx = blockIdx.x * 256 + threadIdx.x;
  if (idx >= 132352) return;
  float acc = 0.0f;
  if (idx < 49152) {
    int h = idx >> 14, rem = idx & 16383, c = rem >> 7, u = rem & 127;
    for (int j = 0; j < 128; ++j)
      acc += We[(size_t)j * 384 + h * 128 + c] * Wee[(size_t)(128 + u) * 128 + j];
    mats[idx] = acc;
  } else if (idx < 58368) {
    int r = idx - 49152; int h = r / 3072; int rem = r - h * 3072; int c = rem / 24; int u = rem - c * 24;
    if (u < 21) {
      int trow = (u < 20) ? (257 + u) : 256;
      for (int j = 0; j < 128; ++j)
        acc += We[(size_t)j * 384 + h * 128 + c] * Wee[(size_t)trow * 128 + j];
    }
    mats[idx] = acc;
  } else if (idx < 107520) {
    int r = idx - 58368; int h = r >> 14; int rem = r & 16383; int tt = rem >> 7; int c = rem & 127;
    for (int j = 0; j < 128; ++j)
      acc += Wee[(size_t)(128 + tt) * 128 + j] * We[(size_t)j * 384 + h * 128 + c];
    mats[idx] = acc;
  } else if (idx < 115584) {
    int r = idx - 107520; int h = r / 2688; int rem = r - h * 2688; int tt = rem >> 7; int c = rem & 127;
    int trow = (tt < 20) ? (257 + tt) : 256;
    for (int j = 0; j < 128; ++j)
      acc += Wee[(size_t)trow * 128 + j] * We[(size_t)j * 384 + h * 128 + c];
    mats[idx] = acc;
  } else if (idx < 115968) {
    int r = idx - 115584; int h = r >> 7; int c = r & 127;
    for (int j = 0; j < 128; ++j)
      acc += bee[j] * We[(size_t)j * 384 + h * 128 + c];
    mats[idx] = acc + be[h * 128 + c];
  } else {
    int r = idx - 115968; int tt = r >> 7; int c = r & 127;
    for (int j = 0; j < 128; ++j)
      acc += Wee[(size_t)tt * 128 + j] *
             (We[(size_t)j * 384 + c] + We[(size_t)j * 384 + 128 + c] + We[(size_t)j * 384 + 256 + c]);
    mats[idx] = acc * (1.0f / 3.0f);
  }
}

// f16 transposed copies for MFMA (WT layout [outcol][k])
__global__ void prep2_kernel(const float* __restrict__ mats, f16* __restrict__ M2T_f,
                             f16* __restrict__ WW2T_f, f16* __restrict__ Ws0T_f)
{
  int idx = blockIdx.x * 256 + threadIdx.x;
  if (idx < 49152) {                  // M2T_f[h][u][k] = mats[h*16384 + k*128 + u]
    int h = idx >> 14, r = idx & 16383, u = r >> 7, k = r & 127;
    M2T_f[idx] = (f16)mats[h * 16384 + k * 128 + u];
  } else if (idx < 98304) {           // WW2T_f[c][h*128+t] = mats[58368 + h*16384 + t*128 + c]
    int r = idx - 49152;
    int c = r / 384; int q = r % 384; int h = q >> 7; int tt = q & 127;
    WW2T_f[r] = (f16)mats[58368 + h * 16384 + tt * 128 + c];
  } else if (idx < 114688) {          // Ws0T_f[c][k] = mats[115968 + k*128 + c]
    int r = idx - 98304; int c = r >> 7, k = r & 127;
    Ws0T_f[r] = (f16)mats[115968 + k * 128 + c];
  }
}

// build f16 WT for the big GEMMs + concatenated bias
__global__ void wprep_kernel(const float* __restrict__ Wq, const float* __restrict__ Wk,
                             const float* __restrict__ Wv, const float* __restrict__ Ws,
                             const float* __restrict__ Wres, const float* __restrict__ Wctr,
                             const float* __restrict__ bq, const float* __restrict__ bk,
                             const float* __restrict__ bv, const float* __restrict__ bs,
                             f16* __restrict__ WTcat, f16* __restrict__ WresT,
                             f16* __restrict__ WctrT, float* __restrict__ biascat)
{
  int idx = blockIdx.x * 256 + threadIdx.x;
  if (idx < 491520) {                 // WTcat[i][c(1280)][k(128)]
    int i = idx / 163840; int r = idx % 163840; int c = r >> 7; int k = r & 127;
    float v;
    if (c < 384)       v = Wq[((size_t)i * 128 + k) * 384 + c];
    else if (c < 768)  v = Wk[((size_t)i * 128 + k) * 384 + (c - 384)];
    else if (c < 1152) v = Wv[((size_t)i * 128 + k) * 384 + (c - 768)];
    else               v = Ws[((size_t)i * 128 + k) * 128 + (c - 1152)];
    WTcat[idx] = (f16)v;
  } else if (idx < 507904) {          // WresT[c][k]
    int r = idx - 491520; int c = r >> 7, k = r & 127;
    WresT[r] = (f16)Wres[k * 128 + c];
  } else if (idx < 540672) {          // WctrT[p][c][k] = Wctr[p*128+k][c]
    int r = idx - 507904; int p = r >> 14; int rr = r & 16383; int c = rr >> 7, k = rr & 127;
    WctrT[r] = (f16)Wctr[((size_t)(p * 128 + k)) * 128 + c];
  } else if (idx < 544512) {          // biascat[i][1280]
    int r = idx - 540672; int i = r / 1280; int c = r % 1280;
    float v;
    if (c < 384)       v = bq[i * 384 + c];
    else if (c < 768)  v = bk[i * 384 + (c - 384)];
    else if (c < 1152) v = bv[i * 384 + (c - 768)];
    else               v = bs[i * 128 + (c - 1152)];
    biascat[r] = v;
  }
}

// ================= g34 = q_h @ M34T  [N][3][24] =================
__global__ __launch_bounds__(256) void g34_kernel(const f16* __restrict__ qkv,
                                                  const float* __restrict__ mats,
                                                  f16* __restrict__ g34b)
{
  __shared__ float xs[32][128];
  const int y = blockIdx.y;
  const float* M34T = mats + 49152 + y * 3072;
  const int n0 = blockIdx.x * 32;
  const int t = threadIdx.x;
  for (int idx = t; idx < 4096; idx += 256) {
    int rr = idx >> 7, kk = idx & 127;
    int n = n0 + rr;
    xs[rr][kk] = (n < NN) ? (float)qkv[(size_t)n * 1152 + y * 128 + kk] : 0.f;
  }
  __syncthreads();
  const int rr = t >> 3;
  const int ub = (t & 7) * 3;
  float a0 = 0.f, a1 = 0.f, a2 = 0.f;
  for (int k = 0; k < 128; ++k) {
    float x = xs[rr][k];
    const float* w = M34T + k * 24 + ub;
    a0 = fmaf(x, w[0], a0); a1 = fmaf(x, w[1], a1); a2 = fmaf(x, w[2], a2);
  }
  int n = n0 + rr;
  if (n < NN) {
    size_t b = ((size_t)n * 3 + y) * 24 + ub;
    g34b[b] = (f16)a0; g34b[b + 1] = (f16)a1; g34b[b + 2] = (f16)a2;
  }
}

// ================= merged-head attention (wave per node, online softmax) =================
__global__ __launch_bounds__(256) void attn_kernel(
    const f16* __restrict__ qkv,     // [N][1152] q|k|v
    const f16* __restrict__ hb,      // [N][128]
    f16* __restrict__ g2fs,          // [N][384] in: g2, out: fs2
    const f16* __restrict__ g34b,    // [N][3][24]
    const int* __restrict__ rowstart,
    const int* __restrict__ srcp,
    const f16* __restrict__ dirpb,
    const int* __restrict__ elist,
    const float* __restrict__ geo,
    const float* __restrict__ mats,  // WWg @107520, bvec @115584
    float* __restrict__ tmp1)
{
  const int lane = threadIdx.x & 63;
  const int n = blockIdx.x * 4 + (threadIdx.x >> 6);
  if (n >= NN) return;
  const float rsC = 0.088388347648318447f;  // 1/sqrt(128)
  const size_t qb = (size_t)n * 1152;
  const size_t gb = (size_t)n * 384;
  float qv[6], ga[6], g34v[3];
#pragma unroll
  for (int tt = 0; tt < 6; ++tt) qv[tt] = (float)qkv[qb + tt * 64 + lane];
#pragma unroll
  for (int tt = 0; tt < 6; ++tt) ga[tt] = (float)g2fs[gb + tt * 64 + lane];
#pragma unroll
  for (int hh = 0; hh < 3; ++hh)
    g34v[hh] = (lane < 21) ? (float)g34b[((size_t)n * 3 + hh) * 24 + lane] : 0.f;
  const int beg = rowstart[n], end = rowstart[n + 1];
  float m[3] = {-INFINITY, -INFINITY, -INFINITY};
  float den[3] = {0.f, 0.f, 0.f};
  float F2[6] = {0,0,0,0,0,0}, av[6] = {0,0,0,0,0,0}, f34[3] = {0,0,0};
  for (int ii = beg; ii < end; ++ii) {
    const int s = srcp[ii];
    const float d = (float)dirpb[ii];
    const size_t kb = (size_t)s * 1152;
    const size_t hbase = (size_t)s * 128;
    float kv[6], vv[6];
#pragma unroll
    for (int tt = 0; tt < 6; ++tt) kv[tt] = (float)qkv[kb + 384 + tt * 64 + lane];
#pragma unroll
    for (int tt = 0; tt < 6; ++tt) vv[tt] = (float)qkv[kb + 768 + tt * 64 + lane];
    const float h0a = (float)hb[hbase + lane];
    const float h0b = (float)hb[hbase + 64 + lane];
    float ge = 0.f;
    if (lane < 20) ge = geo[(size_t)elist[ii] * 20 + lane];
    else if (lane == 20) ge = d;
    float pa[3];
#pragma unroll
    for (int hh = 0; hh < 3; ++hh)
      pa[hh] = qv[2*hh] * kv[2*hh] + qv[2*hh+1] * kv[2*hh+1]
             + d * (ga[2*hh] * h0a + ga[2*hh+1] * h0b) + ge * g34v[hh];
#pragma unroll
    for (int off = 1; off < 64; off <<= 1) {
      pa[0] += __shfl_xor(pa[0], off);
      pa[1] += __shfl_xor(pa[1], off);
      pa[2] += __shfl_xor(pa[2], off);
    }
#pragma unroll
    for (int hh = 0; hh < 3; ++hh) {
      float alpha = pa[hh] * rsC;
      float nm = fmaxf(m[hh], alpha);
      float corr = __expf(m[hh] - nm);   // 0 on first edge (m=-inf)
      float w = __expf(alpha - nm);
      m[hh] = nm;
      den[hh] = den[hh] * corr + w;
      float wd = w * d;
      F2[2*hh]   = F2[2*hh]   * corr + wd * h0a;
      F2[2*hh+1] = F2[2*hh+1] * corr + wd * h0b;
      av[2*hh]   = av[2*hh]   * corr + w * vv[2*hh];
      av[2*hh+1] = av[2*hh+1] * corr + w * vv[2*hh+1];
      f34[hh]    = f34[hh]    * corr + w * ge;
    }
  }
  float sc[3], swh[3];
#pragma unroll
  for (int hh = 0; hh < 3; ++hh) {
    sc[hh] = (1.f / 3.f) / (den[hh] + 1e-16f);   // head-mean folded
    swh[hh] = den[hh] * sc[hh];
  }
#pragma unroll
  for (int tt = 0; tt < 6; ++tt)
    g2fs[gb + tt * 64 + lane] = (f16)(F2[tt] * sc[tt >> 1]);
  float oa = av[0] * sc[0] + av[2] * sc[1] + av[4] * sc[2];
  float ob = av[1] * sc[0] + av[3] * sc[1] + av[5] * sc[2];
  const float* WWg = mats + 107520;
  const float* bvec = mats + 115584;
#pragma unroll
  for (int hh = 0; hh < 3; ++hh) {
    float fh = f34[hh] * sc[hh];
    for (int t2 = 0; t2 < 21; ++t2) {
      float ft = __shfl(fh, t2);
      oa += ft * WWg[hh * 2688 + t2 * 128 + lane];
      ob += ft * WWg[hh * 2688 + t2 * 128 + 64 + lane];
    }
    oa += swh[hh] * bvec[hh * 128 + lane];
    ob += swh[hh] * bvec[hh * 128 + 64 + lane];
  }
  tmp1[(size_t)n * 128 + lane] += oa;
  tmp1[(size_t)n * 128 + 64 + lane] += ob;
}

// ================= elementwise =================
__global__ void finalize_kernel(const float* __restrict__ tmp1, const f16* __restrict__ resid,
                                f16* __restrict__ xnb) {
  int i = blockIdx.x * 256 + threadIdx.x;
  if (i >= NN * 32) return;
  float4 a = ((const float4*)tmp1)[i];
  f16x4 r = ((const f16x4*)resid)[i];
  f16x4 o;
  o[0] = (f16)fmaxf(a.x + (float)r[0], 0.f);
  o[1] = (f16)fmaxf(a.y + (float)r[1], 0.f);
  o[2] = (f16)fmaxf(a.z + (float)r[2], 0.f);
  o[3] = (f16)fmaxf(a.w + (float)r[3], 0.f);
  ((f16x4*)xnb)[i] = o;
}
__global__ void hconv_kernel(const float* __restrict__ src, f16* __restrict__ dst, int n4) {
  int i = blockIdx.x * 256 + threadIdx.x;
  if (i >= n4) return;
  float4 a = ((const float4*)src)[i];
  f16x4 o;
  o[0] = (f16)a.x; o[1] = (f16)a.y; o[2] = (f16)a.z; o[3] = (f16)a.w;
  ((f16x4*)dst)[i] = o;
}

// ================= launch =================
extern "C" void kernel_launch(void* const* d_in, const int* in_sizes, int n_in,
                              void* d_out, int out_size, void* d_ws, size_t ws_size,
                              hipStream_t stream)
{
  (void)in_sizes; (void)n_in; (void)out_size; (void)ws_size;
  const float* h    = (const float*)d_in[0];
  const float* geo  = (const float*)d_in[1];
  const float* dirw = (const float*)d_in[2];
  const int*   src  = (const int*)d_in[3];
  const int*   dst  = (const int*)d_in[4];
  const float* Wee  = (const float*)d_in[5];
  const float* bee  = (const float*)d_in[6];
  const float* Wres = (const float*)d_in[7];
  const float* bres = (const float*)d_in[8];
  const float* Wq   = (const float*)d_in[9];
  const float* bq   = (const float*)d_in[10];
  const float* Wk   = (const float*)d_in[11];
  const float* bk   = (const float*)d_in[12];
  const float* Wv   = (const float*)d_in[13];
  const float* bv   = (const float*)d_in[14];
  const float* We   = (const float*)d_in[15];
  const float* be   = (const float*)d_in[16];
  const float* Ws   = (const float*)d_in[17];
  const float* bs   = (const float*)d_in[18];
  const float* Wctr = (const float*)d_in[19];
  const float* bctr = (const float*)d_in[20];
  float* tmp1 = (float*)d_out;     // d_out doubles as per-layer fp32 accumulator

  char* base = (char*)d_ws;
  size_t off = 0;
  auto take = [&](size_t bytes) -> char* {
    char* p = base + off;
    off += bytes;
    off = (off + 255) & ~(size_t)255;
    return p;
  };
  f16* qkvh    = (f16*)take((size_t)NN * 1152 * 2);
  f16* g2fs    = (f16*)take((size_t)NN * 384 * 2);
  f16* g34b    = (f16*)take((size_t)NN * 72 * 2);
  f16* hb      = (f16*)take((size_t)NN * 128 * 2);
  f16* xb1     = (f16*)take((size_t)NN * 128 * 2);
  f16* xb2     = (f16*)take((size_t)NN * 128 * 2);
  float* mats  = (float*)take(132352 * 4);
  f16* M2T_f   = (f16*)take(49152 * 2);
  f16* WW2T_f  = (f16*)take(49152 * 2);
  f16* Ws0T_f  = (f16*)take(16384 * 2);
  f16* WTcat   = (f16*)take(491520 * 2);
  f16* WresT   = (f16*)take(16384 * 2);
  f16* WctrT   = (f16*)take(32768 * 2);
  float* biascat = (float*)take(3840 * 4);
  float* swc   = (float*)take((size_t)NN * 4);
  f16* dirpb   = (f16*)take((size_t)NE * 2);
  int* deg     = (int*)take((size_t)NN * 4);
  int* rowstart= (int*)take((size_t)(NN + 1) * 4);
  int* cursor  = (int*)take((size_t)NN * 4);
  int* elist   = (int*)take((size_t)NE * 4);
  int* srcp    = (int*)take((size_t)NE * 4);
  int* part    = (int*)take(256 * 4);

  // CSR by dst
  zero_int_kernel<<<(NN + 255) / 256, 256, 0, stream>>>(deg, NN);
  hist_kernel<<<(NE + 255) / 256, 256, 0, stream>>>(dst, deg);
  scanA_kernel<<<196, 256, 0, stream>>>(deg, rowstart, part);
  scanB_kernel<<<1, 256, 0, stream>>>(part, 196);
  scanC_kernel<<<196, 256, 0, stream>>>(deg, rowstart, part, cursor);
  scatter_kernel<<<(NE + 255) / 256, 256, 0, stream>>>(dst, cursor, elist);
  permute_kernel<<<(NE + 255) / 256, 256, 0, stream>>>(elist, src, dirw, srcp, dirpb);
  swc_kernel<<<(NN + 255) / 256, 256, 0, stream>>>(deg, swc);
  hconv_kernel<<<6250, 256, 0, stream>>>(h, hb, NN * 32);
  wprep_kernel<<<(544512 + 255) / 256, 256, 0, stream>>>(Wq, Wk, Wv, Ws, Wres, Wctr,
                                                         bq, bk, bv, bs,
                                                         WTcat, WresT, WctrT, biascat);
  // layer-0 residual (f16) -> xb2
  hgemm_kernel<<<dim3(391, 2, 1), 256, 0, stream>>>(hb, 128, WresT, 128, bres, nullptr,
      nullptr, 0, xb2, 128, 1 << 30, NN, 0, 0, 0, 0);

  const f16* xin = hb;
  for (int i = 0; i < 3; ++i) {
    prep_kernel<<<(132352 + 255) / 256, 256, 0, stream>>>(Wee, bee, We + (size_t)i * 49152,
                                                          be + i * 384, mats);
    prep2_kernel<<<(114688 + 255) / 256, 256, 0, stream>>>(mats, M2T_f, WW2T_f, Ws0T_f);
    // fat: [q|k|v] -> qkvh (f16), skip -> tmp1 (f32)
    hgemm_kernel<<<dim3(391, 20, 1), 256, 0, stream>>>(xin, 128, WTcat + (size_t)i * 163840, 128,
        biascat + i * 1280, nullptr, tmp1, 128, qkvh, 1152, 1152, NN, 0, 0, 0, 0);
    // tmp1 += mask * (h @ Wsum0)
    hgemm_kernel<<<dim3(391, 2, 1), 256, 0, stream>>>(hb, 128, Ws0T_f, 128, nullptr, swc,
        tmp1, 128, nullptr, 0, 0, NN, 1, 0, 0, 0);
    // g2 per head (z-batched) -> g2fs (f16)
    hgemm_kernel<<<dim3(391, 2, 3), 256, 0, stream>>>(qkvh, 1152, M2T_f, 128, nullptr, nullptr,
        nullptr, 0, g2fs, 384, 1 << 30, NN, 0, 128, 16384, 128);
    g34_kernel<<<dim3(1563, 3), 256, 0, stream>>>(qkvh, mats, g34b);
    attn_kernel<<<(NN + 3) / 4, 256, 0, stream>>>(qkvh, hb, g2fs, g34b, rowstart, srcp,
                                                  dirpb, elist, geo, mats, tmp1);
    // tmp1 += fs2 @ WW2 (K=384)
    hgemm_kernel<<<dim3(391, 2, 1), 256, 0, stream>>>(g2fs, 384, WW2T_f, 384, nullptr, nullptr,
        tmp1, 128, nullptr, 0, 0, NN, 1, 0, 0, 0);
    const f16* resid = (i == 0) ? xb2 : xin;
    f16* xout = (i == 1) ? xb2 : xb1;
    finalize_kernel<<<6250, 256, 0, stream>>>(tmp1, resid, xout);
    xin = xout;
  }
  // out = concat(h, h3) @ Wctr + bctr
  hgemm_kernel<<<dim3(391, 2, 1), 256, 0, stream>>>(hb, 128, WctrT, 128, bctr, nullptr,
      tmp1, 128, nullptr, 0, 0, NN, 0, 0, 0, 0);
  hgemm_kernel<<<dim3(391, 2, 1), 256, 0, stream>>>(xin, 128, WctrT + 16384, 128, nullptr, nullptr,
      tmp1, 128, nullptr, 0, 0, NN, 1, 0, 0, 0);
}

// Round 4
// 1562.419 us; speedup vs baseline: 2.3308x; 1.1278x over previous
//
#include <hip/hip_runtime.h>
#include <math.h>

#define NN 50000
#define NE 400000

typedef _Float16 f16;
typedef _Float16 f16x8 __attribute__((ext_vector_type(8)));
typedef _Float16 f16x4 __attribute__((ext_vector_type(4)));
typedef _Float16 f16x2 __attribute__((ext_vector_type(2)));
typedef float f32x4 __attribute__((ext_vector_type(4)));

static __device__ __forceinline__ float dot8(f16x8 a, f16x8 b, float acc) {
#if defined(__has_builtin) && __has_builtin(__builtin_amdgcn_fdot2)
#pragma unroll
  for (int j = 0; j < 4; ++j) {
    f16x2 x = {a[2 * j], a[2 * j + 1]};
    f16x2 y = {b[2 * j], b[2 * j + 1]};
    acc = __builtin_amdgcn_fdot2(x, y, acc, false);
  }
#else
#pragma unroll
  for (int j = 0; j < 8; ++j) acc += (float)a[j] * (float)b[j];
#endif
  return acc;
}

// ================= MFMA fp16 GEMM (proven round 3) =================
__global__ __launch_bounds__(256) void hgemm_kernel(
    const f16* __restrict__ A, int lda,
    const f16* __restrict__ WT, int K,
    const float* __restrict__ bias,
    const float* __restrict__ rowscale,
    float* __restrict__ outf, int ldf,
    f16* __restrict__ outb, int ldb,
    int split_col, int M, int beta,
    int zA, int zW, int zB)
{
  __shared__ f16 As[128 * 128];
  __shared__ f16 Bs[64 * 128];
  const int t = threadIdx.x;
  const int wv = t >> 6, lane = t & 63;
  const int l15 = lane & 15, l4 = lane >> 4;
  const int row0 = blockIdx.x * 128;
  const int col0 = blockIdx.y * 64;
  const int z = blockIdx.z;
  A  += (size_t)z * zA;
  WT += (size_t)z * zW;

  f32x4 acc[2][4];
#pragma unroll
  for (int m = 0; m < 2; ++m)
#pragma unroll
    for (int n = 0; n < 4; ++n) acc[m][n] = (f32x4){0.f, 0.f, 0.f, 0.f};

  for (int kc = 0; kc < K; kc += 128) {
    for (int i = t; i < 2048; i += 256) {
      int r = i >> 4, c8 = i & 15;
      int gr = row0 + r;
      float4 v = make_float4(0.f, 0.f, 0.f, 0.f);
      if (gr < M) v = *(const float4*)(A + (size_t)gr * lda + kc + c8 * 8);
      *(float4*)(As + r * 128 + ((c8 ^ (r & 15)) << 3)) = v;
    }
    for (int i = t; i < 1024; i += 256) {
      int c = i >> 4, c8 = i & 15;
      float4 v = *(const float4*)(WT + (size_t)(col0 + c) * K + kc + c8 * 8);
      *(float4*)(Bs + c * 128 + ((c8 ^ (c & 15)) << 3)) = v;
    }
    __syncthreads();
#pragma unroll
    for (int ks = 0; ks < 4; ++ks) {
      const int co = (((ks * 4 + l4) ^ l15) << 3);
      f16x8 a0 = *(const f16x8*)(As + (wv * 32 +      l15) * 128 + co);
      f16x8 a1 = *(const f16x8*)(As + (wv * 32 + 16 + l15) * 128 + co);
      f16x8 b0 = *(const f16x8*)(Bs + (     l15) * 128 + co);
      f16x8 b1 = *(const f16x8*)(Bs + (16 + l15) * 128 + co);
      f16x8 b2 = *(const f16x8*)(Bs + (32 + l15) * 128 + co);
      f16x8 b3 = *(const f16x8*)(Bs + (48 + l15) * 128 + co);
      acc[0][0] = __builtin_amdgcn_mfma_f32_16x16x32_f16(a0, b0, acc[0][0], 0, 0, 0);
      acc[0][1] = __builtin_amdgcn_mfma_f32_16x16x32_f16(a0, b1, acc[0][1], 0, 0, 0);
      acc[0][2] = __builtin_amdgcn_mfma_f32_16x16x32_f16(a0, b2, acc[0][2], 0, 0, 0);
      acc[0][3] = __builtin_amdgcn_mfma_f32_16x16x32_f16(a0, b3, acc[0][3], 0, 0, 0);
      acc[1][0] = __builtin_amdgcn_mfma_f32_16x16x32_f16(a1, b0, acc[1][0], 0, 0, 0);
      acc[1][1] = __builtin_amdgcn_mfma_f32_16x16x32_f16(a1, b1, acc[1][1], 0, 0, 0);
      acc[1][2] = __builtin_amdgcn_mfma_f32_16x16x32_f16(a1, b2, acc[1][2], 0, 0, 0);
      acc[1][3] = __builtin_amdgcn_mfma_f32_16x16x32_f16(a1, b3, acc[1][3], 0, 0, 0);
    }
    __syncthreads();
  }

  float bv4[4];
#pragma unroll
  for (int n = 0; n < 4; ++n) bv4[n] = bias ? bias[col0 + n * 16 + l15] : 0.f;
#pragma unroll
  for (int m = 0; m < 2; ++m) {
#pragma unroll
    for (int j = 0; j < 4; ++j) {
      int r = row0 + wv * 32 + m * 16 + l4 * 4 + j;
      if (r >= M) continue;
      float rsv = rowscale ? rowscale[r] : 1.f;
#pragma unroll
      for (int n = 0; n < 4; ++n) {
        int c = col0 + n * 16 + l15;
        float val = acc[m][n][j] * rsv + bv4[n];
        if (c < split_col) {
          outb[(size_t)r * ldb + (size_t)z * zB + c] = (f16)val;
        } else {
          float* p = outf + (size_t)r * ldf + (c - split_col);
          *p = (beta ? *p : 0.f) + val;
        }
      }
    }
  }
}

// ================= CSR build =================
__global__ void zero_int_kernel(int* __restrict__ p, int n) {
  int i = blockIdx.x * 256 + threadIdx.x;
  if (i < n) p[i] = 0;
}
__global__ void hist_kernel(const int* __restrict__ dst, int* __restrict__ deg) {
  int e = blockIdx.x * 256 + threadIdx.x;
  if (e < NE) atomicAdd(&deg[dst[e]], 1);
}
__global__ void scanA_kernel(const int* __restrict__ deg, int* __restrict__ rowstart,
                             int* __restrict__ part) {
  __shared__ int sd[256];
  int b = blockIdx.x, t = threadIdx.x, i = b * 256 + t;
  sd[t] = (i < NN) ? deg[i] : 0;
  __syncthreads();
  for (int o = 1; o < 256; o <<= 1) {
    int v = (t >= o) ? sd[t - o] : 0;
    __syncthreads();
    sd[t] += v;
    __syncthreads();
  }
  if (i < NN) rowstart[i + 1] = sd[t];
  if (t == 255) part[b] = sd[255];
}
__global__ void scanB_kernel(int* __restrict__ part, int nb) {
  __shared__ int sd[256];
  int t = threadIdx.x;
  sd[t] = (t < nb) ? part[t] : 0;
  __syncthreads();
  for (int o = 1; o < 256; o <<= 1) {
    int v = (t >= o) ? sd[t - o] : 0;
    __syncthreads();
    sd[t] += v;
    __syncthreads();
  }
  if (t < nb) part[t] = sd[t];
}
__global__ void scanC_kernel(const int* __restrict__ deg, int* __restrict__ rowstart,
                             const int* __restrict__ part, int* __restrict__ cursor) {
  int b = blockIdx.x, t = threadIdx.x, i = b * 256 + t;
  if (i >= NN) return;
  int off = b ? part[b - 1] : 0;
  int fin = rowstart[i + 1] + off;
  rowstart[i + 1] = fin;
  cursor[i] = fin - deg[i];
  if (i == 0) rowstart[0] = 0;
}
__global__ void scatter_kernel(const int* __restrict__ dst, const int* __restrict__ src,
                               const float* __restrict__ dirw,
                               int* __restrict__ cursor, int* __restrict__ elist,
                               int* __restrict__ srcp, f16* __restrict__ dirpb) {
  int e = blockIdx.x * 256 + threadIdx.x;
  if (e < NE) {
    int pos = atomicAdd(&cursor[dst[e]], 1);
    elist[pos] = e;
    srcp[pos] = src[e];
    dirpb[pos] = (f16)dirw[e];
  }
}
__global__ void swc_kernel(const int* __restrict__ deg, float* __restrict__ swc) {
  int n = blockIdx.x * 256 + threadIdx.x;
  if (n < NN) swc[n] = deg[n] ? 1.0f : 0.0f;
}

// ================= per-layer weight prep (batched over 3 layers) =================
// mats[layer]: M2T[3][128(k)][128(u)] @0; M34T[3][128(k)][24] @49152; WW2[3][128(t)][128(c)] @58368;
//              WWg[3][21][128] @107520; bvec[3][128] @115584; Wsum0[128(k)][128(c)] @115968
__global__ void prep_kernel(const float* __restrict__ Wee, const float* __restrict__ bee,
                            const float* __restrict__ WeAll, const float* __restrict__ beAll,
                            float* __restrict__ matsAll)
{
  const int layer = blockIdx.y;
  const float* We = WeAll + (size_t)layer * 49152;
  const float* be = beAll + (size_t)layer * 384;
  float* mats = matsAll + (size_t)layer * 132352;
  int idx = blockIdx.x * 256 + threadIdx.x;
  if (idx >= 132352) return;
  float acc = 0.0f;
  if (idx < 49152) {
    int h = idx >> 14, rem = idx & 16383, c = rem >> 7, u = rem & 127;
    for (int j = 0; j < 128; ++j)
      acc += We[(size_t)j * 384 + h * 128 + c] * Wee[(size_t)(128 + u) * 128 + j];
    mats[idx] = acc;
  } else if (idx < 58368) {
    int r = idx - 49152; int h = r / 3072; int rem = r - h * 3072; int c = rem / 24; int u = rem - c * 24;
    if (u < 21) {
      int trow = (u < 20) ? (257 + u) : 256;
      for (int j = 0; j < 128; ++j)
        acc += We[(size_t)j * 384 + h * 128 + c] * Wee[(size_t)trow * 128 + j];
    }
    mats[idx] = acc;
  } else if (idx < 107520) {
    int r = idx - 58368; int h = r >> 14; int rem = r & 16383; int tt = rem >> 7; int c = rem & 127;
    for (int j = 0; j < 128; ++j)
      acc += Wee[(size_t)(128 + tt) * 128 + j] * We[(size_t)j * 384 + h * 128 + c];
    mats[idx] = acc;
  } else if (idx < 115584) {
    int r = idx - 107520; int h = r / 2688; int rem = r - h * 2688; int tt = rem >> 7; int c = rem & 127;
    int trow = (tt < 20) ? (257 + tt) : 256;
    for (int j = 0; j < 128; ++j)
      acc += Wee[(size_t)trow * 128 + j] * We[(size_t)j * 384 + h * 128 + c];
    mats[idx] = acc;
  } else if (idx < 115968) {
    int r = idx - 115584; int h = r >> 7; int c = r & 127;
    for (int j = 0; j < 128; ++j)
      acc += bee[j] * We[(size_t)j * 384 + h * 128 + c];
    mats[idx] = acc + be[h * 128 + c];
  } else {
    int r = idx - 115968; int tt = r >> 7; int c = r & 127;
    for (int j = 0; j < 128; ++j)
      acc += Wee[(size_t)tt * 128 + j] *
             (We[(size_t)j * 384 + c] + We[(size_t)j * 384 + 128 + c] + We[(size_t)j * 384 + 256 + c]);
    mats[idx] = acc * (1.0f / 3.0f);
  }
}

// f16 transposed copies: M2T_f[3l][3h][128u][128k], W2allT_f[3l][128c][512k], Ws0T_f[3l][128c][128k]
__global__ void prep2_kernel(const float* __restrict__ matsAll, f16* __restrict__ M2T_f,
                             f16* __restrict__ W2allT_f, f16* __restrict__ Ws0T_f)
{
  const int y = blockIdx.y;
  const float* my = matsAll + (size_t)y * 132352;
  int idx = blockIdx.x * 256 + threadIdx.x;
  if (idx < 49152) {
    int h = idx >> 14, r = idx & 16383, u = r >> 7, k = r & 127;
    M2T_f[y * 49152 + idx] = (f16)my[h * 16384 + k * 128 + u];
  } else if (idx < 114688) {
    int r = idx - 49152;
    int c = r >> 9, k = r & 511;
    float v = 0.f;
    if (k < 384) {
      int h = k >> 7, tt = k & 127;
      v = my[58368 + h * 16384 + tt * 128 + c];
    } else if (k < 456) {
      int q = k - 384; int h = q / 24; int tt = q - h * 24;
      if (tt < 21)      v = my[107520 + h * 2688 + tt * 128 + c];
      else if (tt == 21) v = my[115584 + h * 128 + c];
    }
    W2allT_f[y * 65536 + r] = (f16)v;
  } else if (idx < 131072) {
    int r = idx - 114688; int c = r >> 7, k = r & 127;
    Ws0T_f[y * 16384 + r] = (f16)my[115968 + k * 128 + c];
  }
}

// build f16 WT for the big GEMMs + concatenated bias
__global__ void wprep_kernel(const float* __restrict__ Wq, const float* __restrict__ Wk,
                             const float* __restrict__ Wv, const float* __restrict__ Ws,
                             const float* __restrict__ Wres, const float* __restrict__ Wctr,
                             const float* __restrict__ bq, const float* __restrict__ bk,
                             const float* __restrict__ bv, const float* __restrict__ bs,
                             f16* __restrict__ WTcat, f16* __restrict__ WresT,
                             f16* __restrict__ WctrT, float* __restrict__ biascat)
{
  int idx = blockIdx.x * 256 + threadIdx.x;
  if (idx < 491520) {
    int i = idx / 163840; int r = idx % 163840; int c = r >> 7; int k = r & 127;
    float v;
    if (c < 384)       v = Wq[((size_t)i * 128 + k) * 384 + c];
    else if (c < 768)  v = Wk[((size_t)i * 128 + k) * 384 + (c - 384)];
    else if (c < 1152) v = Wv[((size_t)i * 128 + k) * 384 + (c - 768)];
    else               v = Ws[((size_t)i * 128 + k) * 128 + (c - 1152)];
    WTcat[idx] = (f16)v;
  } else if (idx < 507904) {
    int r = idx - 491520; int c = r >> 7, k = r & 127;
    WresT[r] = (f16)Wres[k * 128 + c];
  } else if (idx < 540672) {
    int r = idx - 507904; int p = r >> 14; int rr = r & 16383; int c = rr >> 7, k = rr & 127;
    WctrT[r] = (f16)Wctr[((size_t)(p * 128 + k)) * 128 + c];
  } else if (idx < 544512) {
    int r = idx - 540672; int i = r / 1280; int c = r % 1280;
    float v;
    if (c < 384)       v = bq[i * 384 + c];
    else if (c < 768)  v = bk[i * 384 + (c - 384)];
    else if (c < 1152) v = bv[i * 384 + (c - 768)];
    else               v = bs[i * 128 + (c - 1152)];
    biascat[r] = v;
  }
}

// ================= g34 = q_h @ M34T  [N][3][24] =================
__global__ __launch_bounds__(256) void g34_kernel(const f16* __restrict__ qkv,
                                                  const float* __restrict__ mats,
                                                  f16* __restrict__ g34b)
{
  __shared__ float xs[32][128];
  const int y = blockIdx.y;
  const float* M34T = mats + 49152 + y * 3072;
  const int n0 = blockIdx.x * 32;
  const int t = threadIdx.x;
  for (int idx = t; idx < 4096; idx += 256) {
    int rr = idx >> 7, kk = idx & 127;
    int n = n0 + rr;
    xs[rr][kk] = (n < NN) ? (float)qkv[(size_t)n * 1152 + y * 128 + kk] : 0.f;
  }
  __syncthreads();
  const int rr = t >> 3;
  const int ub = (t & 7) * 3;
  float a0 = 0.f, a1 = 0.f, a2 = 0.f;
  for (int k = 0; k < 128; ++k) {
    float x = xs[rr][k];
    const float* w = M34T + k * 24 + ub;
    a0 = fmaf(x, w[0], a0); a1 = fmaf(x, w[1], a1); a2 = fmaf(x, w[2], a2);
  }
  int n = n0 + rr;
  if (n < NN) {
    size_t b = ((size_t)n * 3 + y) * 24 + ub;
    g34b[b] = (f16)a0; g34b[b + 1] = (f16)a1; g34b[b + 2] = (f16)a2;
  }
}

// ================= attention v2: 16 lanes/node, 4 nodes/wave, no online-max =================
// g2all [N][512]: cols 0..383 in=g2 out=fs2; cols 384..455 out=fg (geo/den sums); 456..511 zero.
__global__ __launch_bounds__(256) void attn_kernel(
    const f16* __restrict__ qkv,
    const f16* __restrict__ hb,
    f16* __restrict__ g2all,
    const f16* __restrict__ g34b,
    const int* __restrict__ rowstart,
    const int* __restrict__ srcp,
    const f16* __restrict__ dirpb,
    const int* __restrict__ elist,
    const float* __restrict__ geo,
    float* __restrict__ tmp1)
{
  const int sl = threadIdx.x & 15;
  const int n = blockIdx.x * 16 + (threadIdx.x >> 4);
  const float rsC = 0.088388347648318447f;  // 1/sqrt(128)

  const size_t qbase = (size_t)n * 1152 + sl * 8;
  f16x8 qv0 = *(const f16x8*)(qkv + qbase);
  f16x8 qv1 = *(const f16x8*)(qkv + qbase + 128);
  f16x8 qv2 = *(const f16x8*)(qkv + qbase + 256);
  const size_t g2base = (size_t)n * 512 + sl * 8;
  f16x8 ga0 = *(const f16x8*)(g2all + g2base);
  f16x8 ga1 = *(const f16x8*)(g2all + g2base + 128);
  f16x8 ga2 = *(const f16x8*)(g2all + g2base + 256);
  float g34a[3], g34c[3];
#pragma unroll
  for (int h = 0; h < 3; ++h) {
    g34a[h] = (float)g34b[((size_t)n * 3 + h) * 24 + sl];
    g34c[h] = (sl < 8) ? (float)g34b[((size_t)n * 3 + h) * 24 + 16 + sl] : 0.f;
  }
  float den0 = 0.f, den1 = 0.f, den2 = 0.f;
  float F2[3][8], av[3][8];
#pragma unroll
  for (int h = 0; h < 3; ++h)
#pragma unroll
    for (int j = 0; j < 8; ++j) { F2[h][j] = 0.f; av[h][j] = 0.f; }
  float f34a0 = 0.f, f34a1 = 0.f, f34a2 = 0.f;
  float f34c0 = 0.f, f34c1 = 0.f, f34c2 = 0.f;

  const int beg = rowstart[n], end = rowstart[n + 1];
  for (int ii = beg; ii < end; ++ii) {
    const int s = srcp[ii];
    const int e = elist[ii];
    const float d = (float)dirpb[ii];
    const f16* kp = qkv + (size_t)s * 1152 + sl * 8;
    f16x8 kv0 = *(const f16x8*)(kp + 384);
    f16x8 kv1 = *(const f16x8*)(kp + 512);
    f16x8 kv2 = *(const f16x8*)(kp + 640);
    f16x8 vv0 = *(const f16x8*)(kp + 768);
    f16x8 vv1 = *(const f16x8*)(kp + 896);
    f16x8 vv2 = *(const f16x8*)(kp + 1024);
    f16x8 h0v = *(const f16x8*)(hb + (size_t)s * 128 + sl * 8);
    float ge_a = geo[(size_t)e * 20 + sl];
    float ge_b = (sl < 4) ? geo[(size_t)e * 20 + 16 + sl] : (sl == 4 ? d : 0.f);

    float pa0 = dot8(qv0, kv0, 0.f) + d * dot8(ga0, h0v, 0.f) + ge_a * g34a[0] + ge_b * g34c[0];
    float pa1 = dot8(qv1, kv1, 0.f) + d * dot8(ga1, h0v, 0.f) + ge_a * g34a[1] + ge_b * g34c[1];
    float pa2 = dot8(qv2, kv2, 0.f) + d * dot8(ga2, h0v, 0.f) + ge_a * g34a[2] + ge_b * g34c[2];
#pragma unroll
    for (int off = 1; off < 16; off <<= 1) {
      pa0 += __shfl_xor(pa0, off);
      pa1 += __shfl_xor(pa1, off);
      pa2 += __shfl_xor(pa2, off);
    }
    const float w0 = __expf(pa0 * rsC);
    const float w1 = __expf(pa1 * rsC);
    const float w2 = __expf(pa2 * rsC);
    den0 += w0; den1 += w1; den2 += w2;
    const float wd0 = w0 * d, wd1 = w1 * d, wd2 = w2 * d;
#pragma unroll
    for (int j = 0; j < 8; ++j) {
      const float hf = (float)h0v[j];
      F2[0][j] = fmaf(wd0, hf, F2[0][j]);
      F2[1][j] = fmaf(wd1, hf, F2[1][j]);
      F2[2][j] = fmaf(wd2, hf, F2[2][j]);
      av[0][j] = fmaf(w0, (float)vv0[j], av[0][j]);
      av[1][j] = fmaf(w1, (float)vv1[j], av[1][j]);
      av[2][j] = fmaf(w2, (float)vv2[j], av[2][j]);
    }
    f34a0 = fmaf(w0, ge_a, f34a0); f34a1 = fmaf(w1, ge_a, f34a1); f34a2 = fmaf(w2, ge_a, f34a2);
    f34c0 = fmaf(w0, ge_b, f34c0); f34c1 = fmaf(w1, ge_b, f34c1); f34c2 = fmaf(w2, ge_b, f34c2);
  }

  float sc[3], swh[3], dens[3] = {den0, den1, den2};
  float f34av[3] = {f34a0, f34a1, f34a2}, f34cv[3] = {f34c0, f34c1, f34c2};
#pragma unroll
  for (int h = 0; h < 3; ++h) {
    sc[h] = (1.f / 3.f) / (dens[h] + 1e-16f);
    swh[h] = dens[h] * sc[h];
  }
  // fs2 out
#pragma unroll
  for (int h = 0; h < 3; ++h) {
    f16x8 o;
#pragma unroll
    for (int j = 0; j < 8; ++j) o[j] = (f16)(F2[h][j] * sc[h]);
    *(f16x8*)(g2all + g2base + h * 128) = o;
  }
  // fg out (geo sums + den marker)
#pragma unroll
  for (int h = 0; h < 3; ++h) {
    g2all[(size_t)n * 512 + 384 + h * 24 + sl] = (f16)(f34av[h] * sc[h]);
    if (sl < 8) {
      float fcv = (sl == 5) ? swh[h] : f34cv[h] * sc[h];
      g2all[(size_t)n * 512 + 384 + h * 24 + 16 + sl] = (f16)fcv;
    }
  }
  // head-mean v accumulation -> tmp1 RMW
  float* tp = tmp1 + (size_t)n * 128 + sl * 8;
  float4 t0 = *(float4*)tp;
  float4 t1 = *(float4*)(tp + 4);
  t0.x += av[0][0] * sc[0] + av[1][0] * sc[1] + av[2][0] * sc[2];
  t0.y += av[0][1] * sc[0] + av[1][1] * sc[1] + av[2][1] * sc[2];
  t0.z += av[0][2] * sc[0] + av[1][2] * sc[1] + av[2][2] * sc[2];
  t0.w += av[0][3] * sc[0] + av[1][3] * sc[1] + av[2][3] * sc[2];
  t1.x += av[0][4] * sc[0] + av[1][4] * sc[1] + av[2][4] * sc[2];
  t1.y += av[0][5] * sc[0] + av[1][5] * sc[1] + av[2][5] * sc[2];
  t1.z += av[0][6] * sc[0] + av[1][6] * sc[1] + av[2][6] * sc[2];
  t1.w += av[0][7] * sc[0] + av[1][7] * sc[1] + av[2][7] * sc[2];
  *(float4*)tp = t0;
  *(float4*)(tp + 4) = t1;
}

// ================= elementwise =================
__global__ void finalize_kernel(const float* __restrict__ tmp1, const f16* __restrict__ resid,
                                f16* __restrict__ xnb) {
  int i = blockIdx.x * 256 + threadIdx.x;
  if (i >= NN * 32) return;
  float4 a = ((const float4*)tmp1)[i];
  f16x4 r = ((const f16x4*)resid)[i];
  f16x4 o;
  o[0] = (f16)fmaxf(a.x + (float)r[0], 0.f);
  o[1] = (f16)fmaxf(a.y + (float)r[1], 0.f);
  o[2] = (f16)fmaxf(a.z + (float)r[2], 0.f);
  o[3] = (f16)fmaxf(a.w + (float)r[3], 0.f);
  ((f16x4*)xnb)[i] = o;
}
__global__ void hconv_kernel(const float* __restrict__ src, f16* __restrict__ dst, int n4) {
  int i = blockIdx.x * 256 + threadIdx.x;
  if (i >= n4) return;
  float4 a = ((const float4*)src)[i];
  f16x4 o;
  o[0] = (f16)a.x; o[1] = (f16)a.y; o[2] = (f16)a.z; o[3] = (f16)a.w;
  ((f16x4*)dst)[i] = o;
}

// ================= launch =================
extern "C" void kernel_launch(void* const* d_in, const int* in_sizes, int n_in,
                              void* d_out, int out_size, void* d_ws, size_t ws_size,
                              hipStream_t stream)
{
  (void)in_sizes; (void)n_in; (void)out_size; (void)ws_size;
  const float* h    = (const float*)d_in[0];
  const float* geo  = (const float*)d_in[1];
  const float* dirw = (const float*)d_in[2];
  const int*   src  = (const int*)d_in[3];
  const int*   dst  = (const int*)d_in[4];
  const float* Wee  = (const float*)d_in[5];
  const float* bee  = (const float*)d_in[6];
  const float* Wres = (const float*)d_in[7];
  const float* bres = (const float*)d_in[8];
  const float* Wq   = (const float*)d_in[9];
  const float* bq   = (const float*)d_in[10];
  const float* Wk   = (const float*)d_in[11];
  const float* bk   = (const float*)d_in[12];
  const float* Wv   = (const float*)d_in[13];
  const float* bv   = (const float*)d_in[14];
  const float* We   = (const float*)d_in[15];
  const float* be   = (const float*)d_in[16];
  const float* Ws   = (const float*)d_in[17];
  const float* bs   = (const float*)d_in[18];
  const float* Wctr = (const float*)d_in[19];
  const float* bctr = (const float*)d_in[20];
  float* tmp1 = (float*)d_out;     // d_out doubles as per-layer fp32 accumulator

  char* base = (char*)d_ws;
  size_t off = 0;
  auto take = [&](size_t bytes) -> char* {
    char* p = base + off;
    off += bytes;
    off = (off + 255) & ~(size_t)255;
    return p;
  };
  f16* qkvh     = (f16*)take((size_t)NN * 1152 * 2);
  f16* g2all    = (f16*)take((size_t)NN * 512 * 2);
  f16* g34b     = (f16*)take((size_t)NN * 72 * 2);
  f16* hb       = (f16*)take((size_t)NN * 128 * 2);
  f16* xb1      = (f16*)take((size_t)NN * 128 * 2);
  f16* xb2      = (f16*)take((size_t)NN * 128 * 2);
  float* mats   = (float*)take((size_t)3 * 132352 * 4);
  f16* M2T_f    = (f16*)take((size_t)3 * 49152 * 2);
  f16* W2allT_f = (f16*)take((size_t)3 * 65536 * 2);
  f16* Ws0T_f   = (f16*)take((size_t)3 * 16384 * 2);
  f16* WTcat    = (f16*)take(491520 * 2);
  f16* WresT    = (f16*)take(16384 * 2);
  f16* WctrT    = (f16*)take(32768 * 2);
  float* biascat = (float*)take(3840 * 4);
  float* swc    = (float*)take((size_t)NN * 4);
  f16* dirpb    = (f16*)take((size_t)NE * 2);
  int* deg      = (int*)take((size_t)NN * 4);
  int* rowstart = (int*)take((size_t)(NN + 1) * 4);
  int* cursor   = (int*)take((size_t)NN * 4);
  int* elist    = (int*)take((size_t)NE * 4);
  int* srcp     = (int*)take((size_t)NE * 4);
  int* part     = (int*)take(256 * 4);

  // CSR by dst
  zero_int_kernel<<<(NN + 255) / 256, 256, 0, stream>>>(deg, NN);
  hist_kernel<<<(NE + 255) / 256, 256, 0, stream>>>(dst, deg);
  scanA_kernel<<<196, 256, 0, stream>>>(deg, rowstart, part);
  scanB_kernel<<<1, 256, 0, stream>>>(part, 196);
  scanC_kernel<<<196, 256, 0, stream>>>(deg, rowstart, part, cursor);
  scatter_kernel<<<(NE + 255) / 256, 256, 0, stream>>>(dst, src, dirw, cursor, elist, srcp, dirpb);
  swc_kernel<<<(NN + 255) / 256, 256, 0, stream>>>(deg, swc);
  hconv_kernel<<<6250, 256, 0, stream>>>(h, hb, NN * 32);
  wprep_kernel<<<(544512 + 255) / 256, 256, 0, stream>>>(Wq, Wk, Wv, Ws, Wres, Wctr,
                                                         bq, bk, bv, bs,
                                                         WTcat, WresT, WctrT, biascat);
  prep_kernel<<<dim3(518, 3), 256, 0, stream>>>(Wee, bee, We, be, mats);
  prep2_kernel<<<dim3(512, 3), 256, 0, stream>>>(mats, M2T_f, W2allT_f, Ws0T_f);
  zero_int_kernel<<<(NN * 256 + 255) / 256, 256, 0, stream>>>((int*)g2all, NN * 256);

  // layer-0 residual (f16) -> xb2
  hgemm_kernel<<<dim3(391, 2, 1), 256, 0, stream>>>(hb, 128, WresT, 128, bres, nullptr,
      nullptr, 0, xb2, 128, 1 << 30, NN, 0, 0, 0, 0);

  const f16* xin = hb;
  for (int i = 0; i < 3; ++i) {
    // fat: [q|k|v] -> qkvh (f16), skip -> tmp1 (f32, fresh)
    hgemm_kernel<<<dim3(391, 20, 1), 256, 0, stream>>>(xin, 128, WTcat + (size_t)i * 163840, 128,
        biascat + i * 1280, nullptr, tmp1, 128, qkvh, 1152, 1152, NN, 0, 0, 0, 0);
    // tmp1 += mask * (h @ Wsum0)
    hgemm_kernel<<<dim3(391, 2, 1), 256, 0, stream>>>(hb, 128, Ws0T_f + (size_t)i * 16384, 128,
        nullptr, swc, tmp1, 128, nullptr, 0, 0, NN, 1, 0, 0, 0);
    // g2 per head (z-batched) -> g2all cols 0..383
    hgemm_kernel<<<dim3(391, 2, 3), 256, 0, stream>>>(qkvh, 1152, M2T_f + (size_t)i * 49152, 128,
        nullptr, nullptr, nullptr, 0, g2all, 512, 1 << 30, NN, 0, 128, 16384, 128);
    g34_kernel<<<dim3(1563, 3), 256, 0, stream>>>(qkvh, mats + (size_t)i * 132352, g34b);
    attn_kernel<<<3125, 256, 0, stream>>>(qkvh, hb, g2all, g34b, rowstart, srcp,
                                          dirpb, elist, geo, tmp1);
    // tmp1 += [fs2 | fg] @ W2all (K=512)
    hgemm_kernel<<<dim3(391, 2, 1), 256, 0, stream>>>(g2all, 512, W2allT_f + (size_t)i * 65536, 512,
        nullptr, nullptr, tmp1, 128, nullptr, 0, 0, NN, 1, 0, 0, 0);
    const f16* resid = (i == 0) ? xb2 : xin;
    f16* xout = (i == 1) ? xb2 : xb1;
    finalize_kernel<<<6250, 256, 0, stream>>>(tmp1, resid, xout);
    xin = xout;
  }
  // out = concat(h, h3) @ Wctr + bctr
  hgemm_kernel<<<dim3(391, 2, 1), 256, 0, stream>>>(hb, 128, WctrT, 128, bctr, nullptr,
      tmp1, 128, nullptr, 0, 0, NN, 0, 0, 0, 0);
  hgemm_kernel<<<dim3(391, 2, 1), 256, 0, stream>>>(xin, 128, WctrT + 16384, 128, nullptr, nullptr,
      tmp1, 128, nullptr, 0, 0, NN, 1, 0, 0, 0);
}